// Round 2
// baseline (1158.940 us; speedup 1.0000x reference)
//
#include <hip/hip_runtime.h>
#include <stdint.h>

#define TPB 256

typedef short s4v __attribute__((ext_vector_type(4)));
typedef short s8v __attribute__((ext_vector_type(8)));
typedef float f4v __attribute__((ext_vector_type(4)));

__device__ __forceinline__ unsigned short f2bf(float f) {
  union { float f; unsigned u; } v; v.f = f;
  unsigned r = v.u + 0x7FFFu + ((v.u >> 16) & 1u);
  return (unsigned short)(r >> 16);
}
__device__ __forceinline__ float bf2f(unsigned short h) {
  union { unsigned u; float f; } v; v.u = ((unsigned)h) << 16;
  return v.f;
}
__device__ __forceinline__ void gl_lds16(const void* g, void* l) {
  __builtin_amdgcn_global_load_lds(
      (const __attribute__((address_space(1))) void*)g,
      (__attribute__((address_space(3))) void*)l, 16, 0, 0);
}

// ---------------- small prep kernels ----------------

__global__ void k_cast_bf16(const float* __restrict__ src, unsigned short* __restrict__ dst, int n4) {
  int i = blockIdx.x * TPB + threadIdx.x;
  if (i >= n4) return;
  float4 v = ((const float4*)src)[i];
  ushort4 o;
  o.x = f2bf(v.x); o.y = f2bf(v.y); o.z = f2bf(v.z); o.w = f2bf(v.w);
  ((ushort4*)dst)[i] = o;
}

// wmT[dir][d][t] = w_merge[(dir*512+t)*512 + d]  (bf16)
__global__ void k_prep_wmT(const float* __restrict__ wm, unsigned short* __restrict__ dst) {
  int id = blockIdx.x * TPB + threadIdx.x;  // 4*512*512
  int dir = id >> 18, rem = id & 262143, d = rem >> 9, t = rem & 511;
  dst[id] = f2bf(wm[(size_t)(dir * 512 + t) * 512 + d]);
}

// B1t[j][k]: interleaved-by-16 z/gate columns of w_in, transposed (N-major)
__global__ void k_prep_b1(const float* __restrict__ w_in, const float* __restrict__ b_in,
                          unsigned short* __restrict__ B1t, float* __restrict__ bb1) {
  int id = blockIdx.x * TPB + threadIdx.x;  // 8192*512
  int j = id >> 9, k = id & 511;
  int g = j >> 5, o = j & 31, s = o >> 4, c = o & 15;
  int dir = g >> 6;
  int e = ((g & 63) << 4) + c;
  B1t[id] = f2bf(w_in[(size_t)(dir * 512 + k) * 2048 + s * 1024 + e]);
  if (k == 0) bb1[j] = b_in[dir * 2048 + s * 1024 + e];
}

// v[dir][t] = sum_e ln_b[dir][e] * w_out[dir][e][t]
__global__ void k_prep_v(const float* __restrict__ lnb, const float* __restrict__ wout,
                         float* __restrict__ v) {
  int id = blockIdx.x * TPB + threadIdx.x;  // 2048
  int dir = id >> 9, t = id & 511;
  float s = 0.f;
  for (int e = 0; e < 1024; ++e)
    s += lnb[dir * 1024 + e] * wout[(size_t)(dir * 1024 + e) * 512 + t];
  v[id] = s;
}

// bias2[d] = b_merge[d] + sum_{dir,t} (b_out[dir][t] + v[dir][t]) * w_merge[(dir*512+t)][d]
__global__ void k_prep_bias2(const float* __restrict__ bmerge, const float* __restrict__ bout,
                             const float* __restrict__ v, const float* __restrict__ wmerge,
                             float* __restrict__ bias2) {
  int d = blockIdx.x * TPB + threadIdx.x;  // 512
  if (d >= 512) return;
  float s = bmerge[d];
  for (int f = 0; f < 2048; ++f)
    s += (bout[f] + v[f]) * wmerge[(size_t)f * 512 + d];
  bias2[d] = s;
}

// ---------------- GEMM template ----------------
// C[M,N] = A[M,K] * Bt[N,K]^T, bf16 inputs, 128x128 tile, BK=64, 4 waves.
// MODE 0: K1 (gating epilogue + atomic LN stats -> Z bf16); rows are chunk-local
// MODE 1: K2 (+bias2 -> f32 out); rows chunk-local
// MODE 2: W2' build (scale by ln_g, scatter-write transposed bf16)
template <int MODE>
__launch_bounds__(TPB, 2)
__global__ void k_gemm(const unsigned short* __restrict__ A,
                       const unsigned short* __restrict__ Bt, int K,
                       unsigned short* __restrict__ U16out, float* __restrict__ F32out,
                       const float* __restrict__ bb1, float* __restrict__ gsum,
                       float* __restrict__ gsq, const float* __restrict__ bias2,
                       const float* __restrict__ lng) {
  __shared__ char lds[2][32768];
  const int tid = threadIdx.x;
  const int bN = blockIdx.x, bM = blockIdx.y;
  const int lane = tid & 63, wid = tid >> 6;
  const int wm = wid >> 1, wn = wid & 1;
  const int q = lane >> 4, c = lane & 15;

  const unsigned short* Bte = Bt;
  if (MODE == 2) Bte += (size_t)(bM >> 3) * (512 * 512);

  const size_t ldab = (size_t)K * 2;  // row stride in bytes
  const char* Ab = (const char*)A + (size_t)bM * 128 * ldab;
  const char* Bb = (const char*)Bte + (size_t)bN * 128 * ldab;

  f4v acc[4][4];
  {
    f4v z = {0.f, 0.f, 0.f, 0.f};
#pragma unroll
    for (int m = 0; m < 4; ++m)
#pragma unroll
      for (int n = 0; n < 4; ++n) acc[m][n] = z;
  }

  const int NT = K >> 6;

  auto stage = [&](int buf, int kt) {
    const size_t kb = (size_t)kt << 7;  // kt*64 elems * 2B
#pragma unroll
    for (int i = 0; i < 4; ++i) {
      int ci = tid + i * 256;
      int r = ci >> 3, cc = ci & 7;
      int ccs = cc ^ (r & 7);  // pre-swizzled global source (rule 21)
      gl_lds16(Ab + (size_t)r * ldab + kb + ccs * 16,
               (void*)(lds[buf] + wid * 1024 + i * 4096));
    }
#pragma unroll
    for (int i = 0; i < 4; ++i) {
      int ci = tid + i * 256;
      int r = ci >> 3, cc = ci & 7;
      int ccs = cc ^ (r & 7);
      gl_lds16(Bb + (size_t)r * ldab + kb + ccs * 16,
               (void*)(lds[buf] + 16384 + wid * 1024 + i * 4096));
    }
  };

  stage(0, 0);
  __syncthreads();

  for (int t = 0; t < NT; ++t) {
    const int cur = t & 1;
    if (t + 1 < NT) stage(cur ^ 1, t + 1);
    const char* L = lds[cur];
#pragma unroll
    for (int kk = 0; kk < 2; ++kk) {
      s8v af[4], bfr[4];
#pragma unroll
      for (int m = 0; m < 4; ++m) {
        int r = wm * 64 + m * 16 + c;
        int sw = ((r << 7) + (kk << 6) + (q << 3)) ^ ((r & 7) << 4);
        s4v lo = *(const s4v*)(L + sw);
        s4v hi = *(const s4v*)(L + (sw ^ 32));
        af[m] = __builtin_shufflevector(lo, hi, 0, 1, 2, 3, 4, 5, 6, 7);
      }
#pragma unroll
      for (int n = 0; n < 4; ++n) {
        int r = wn * 64 + n * 16 + c;
        int sw = ((r << 7) + (kk << 6) + (q << 3)) ^ ((r & 7) << 4);
        s4v lo = *(const s4v*)(L + 16384 + sw);
        s4v hi = *(const s4v*)(L + 16384 + (sw ^ 32));
        bfr[n] = __builtin_shufflevector(lo, hi, 0, 1, 2, 3, 4, 5, 6, 7);
      }
#pragma unroll
      for (int m = 0; m < 4; ++m)
#pragma unroll
        for (int n = 0; n < 4; ++n)
          acc[m][n] = __builtin_amdgcn_mfma_f32_16x16x32_bf16(af[m], bfr[n], acc[m][n], 0, 0, 0);
    }
    __syncthreads();
  }

  if (MODE == 0) {
    const int dir = bN >> 4;
    float s1[4][4], s2[4][4];
#pragma unroll
    for (int m = 0; m < 4; ++m)
#pragma unroll
      for (int r = 0; r < 4; ++r) { s1[m][r] = 0.f; s2[m][r] = 0.f; }
#pragma unroll
    for (int tt = 0; tt < 2; ++tt) {
      const int jz = bN * 128 + wn * 64 + tt * 32 + c;
      const float bbz = bb1[jz], bbg = bb1[jz + 16];
      const int e = ((bN * 4 + wn * 2 + tt) & 63) * 16 + c;
#pragma unroll
      for (int m = 0; m < 4; ++m) {
        f4v z4 = acc[m][2 * tt], g4 = acc[m][2 * tt + 1];
#pragma unroll
        for (int r = 0; r < 4; ++r) {
          int row = bM * 128 + wm * 64 + m * 16 + q * 4 + r;
          float zv = z4[r] + bbz, gv = g4[r] + bbg;
          float gated = zv * (1.f / (1.f + __expf(-zv))) * (1.f / (1.f + __expf(-gv)));
          U16out[(size_t)row * 4096 + dir * 1024 + e] = f2bf(gated);
          s1[m][r] += gated;
          s2[m][r] += gated * gated;
        }
      }
    }
#pragma unroll
    for (int m = 0; m < 4; ++m)
#pragma unroll
      for (int r = 0; r < 4; ++r) {
        float a1 = s1[m][r], a2 = s2[m][r];
#pragma unroll
        for (int mk = 1; mk < 16; mk <<= 1) {
          a1 += __shfl_xor(a1, mk);
          a2 += __shfl_xor(a2, mk);
        }
        if (c == 0) {
          int row = bM * 128 + wm * 64 + m * 16 + q * 4 + r;
          atomicAdd(&gsum[row * 4 + dir], a1);
          atomicAdd(&gsq[row * 4 + dir], a2);
        }
      }
  }

  if (MODE == 1) {
#pragma unroll
    for (int n = 0; n < 4; ++n) {
      int col = bN * 128 + wn * 64 + n * 16 + c;
      float b2 = bias2[col];
#pragma unroll
      for (int m = 0; m < 4; ++m)
#pragma unroll
        for (int r = 0; r < 4; ++r) {
          int row = bM * 128 + wm * 64 + m * 16 + q * 4 + r;
          F32out[(size_t)row * 512 + col] = acc[m][n][r] + b2;
        }
    }
  }

  if (MODE == 2) {
#pragma unroll
    for (int m = 0; m < 4; ++m)
#pragma unroll
      for (int r = 0; r < 4; ++r) {
        int f = bM * 128 + wm * 64 + m * 16 + q * 4 + r;
        float sc = lng[f];
#pragma unroll
        for (int n = 0; n < 4; ++n) {
          int d = bN * 128 + wn * 64 + n * 16 + c;
          U16out[(size_t)d * 4096 + f] = f2bf(acc[m][n][r] * sc);
        }
      }
  }
}

// ---------------- post kernels ----------------

__global__ void k_stats(const float* __restrict__ gsum, const float* __restrict__ gsq,
                        float* __restrict__ mu, float* __restrict__ rs, int n) {
  int i = blockIdx.x * TPB + threadIdx.x;
  if (i >= n) return;
  float m = gsum[i] * (1.f / 1024.f);
  float v = gsq[i] * (1.f / 1024.f) - m * m;
  mu[i] = m;
  rs[i] = rsqrtf(fmaxf(v, 0.f) + 1e-5f);
}

__global__ void k_norm(unsigned short* __restrict__ Z, const float* __restrict__ mu,
                       const float* __restrict__ rs) {
  size_t gt = (size_t)blockIdx.x * TPB + threadIdx.x;
  size_t i = gt * 8;  // 8 bf16 per thread, same (row,dir)
  int row = (int)(i >> 12);
  int dir = (int)((i >> 10) & 3);
  float m = mu[row * 4 + dir], r = rs[row * 4 + dir];
  s8v v = *(s8v*)(Z + i);
#pragma unroll
  for (int j = 0; j < 8; ++j) {
    float x = bf2f((unsigned short)v[j]);
    v[j] = (short)f2bf((x - m) * r);
  }
  *(s8v*)(Z + i) = v;
}

__global__ void k_final_ln(float* __restrict__ out, const float* __restrict__ g,
                           const float* __restrict__ b) {
  int row = blockIdx.x * 4 + (threadIdx.x >> 6);
  int lane = threadIdx.x & 63;
  float* p = out + (size_t)row * 512;
  float x[8];
  *(float4*)&x[0] = *(const float4*)(p + lane * 4);
  *(float4*)&x[4] = *(const float4*)(p + 256 + lane * 4);
  float s = 0.f;
#pragma unroll
  for (int j = 0; j < 8; ++j) s += x[j];
#pragma unroll
  for (int mk = 1; mk < 64; mk <<= 1) s += __shfl_xor(s, mk);
  float mean = s * (1.f / 512.f);
  float vs = 0.f;
#pragma unroll
  for (int j = 0; j < 8; ++j) { float d = x[j] - mean; vs += d * d; }
#pragma unroll
  for (int mk = 1; mk < 64; mk <<= 1) vs += __shfl_xor(vs, mk);
  float rstd = rsqrtf(vs * (1.f / 512.f) + 1e-5f);
  float gg[8], bb[8];
  *(float4*)&gg[0] = *(const float4*)(g + lane * 4);
  *(float4*)&gg[4] = *(const float4*)(g + 256 + lane * 4);
  *(float4*)&bb[0] = *(const float4*)(b + lane * 4);
  *(float4*)&bb[4] = *(const float4*)(b + 256 + lane * 4);
#pragma unroll
  for (int j = 0; j < 8; ++j) x[j] = (x[j] - mean) * rstd * gg[j] + bb[j];
  *(float4*)(p + lane * 4) = *(float4*)&x[0];
  *(float4*)(p + 256 + lane * 4) = *(float4*)&x[4];
}

// ---------------- launch ----------------

extern "C" void kernel_launch(void* const* d_in, const int* in_sizes, int n_in,
                              void* d_out, int out_size, void* d_ws, size_t ws_size,
                              hipStream_t stream) {
  const float* x     = (const float*)d_in[0];
  const float* w_in  = (const float*)d_in[1];
  const float* b_in  = (const float*)d_in[2];
  const float* ln_g  = (const float*)d_in[3];
  const float* ln_b  = (const float*)d_in[4];
  const float* w_out = (const float*)d_in[5];
  const float* b_out = (const float*)d_in[6];
  const float* w_mrg = (const float*)d_in[7];
  const float* b_mrg = (const float*)d_in[8];
  const float* nrm_g = (const float*)d_in[9];
  const float* nrm_b = (const float*)d_in[10];
  float* out = (float*)d_out;

  char* ws = (char*)d_ws;
  size_t off = 0;
  auto take = [&](size_t bytes) {
    char* p = ws + off;
    off += (bytes + 255) & ~(size_t)255;
    return p;
  };
  unsigned short* Xb    = (unsigned short*)take(33554432);   // x bf16 [32768][512]
  unsigned short* B1t   = (unsigned short*)take(8388608);    // w_in arranged [8192][512]
  float*          bb1   = (float*)take(32768);               // arranged b_in
  unsigned short* Wob   = (unsigned short*)take(4194304);    // w_out bf16 [4096][512]
  unsigned short* WmT   = (unsigned short*)take(2097152);    // w_merge^T bf16 [4][512][512]
  unsigned short* W2p   = (unsigned short*)take(4194304);    // combined W2' [512][4096]
  float*          vbuf  = (float*)take(8192);
  float*          bias2 = (float*)take(2048);
  float*          gsum  = (float*)take(524288);
  float*          gsq   = (float*)take(524288);
  float*          mu    = (float*)take(524288);
  float*          rs    = (float*)take(524288);
  size_t fixed = off;

  // Chunk size R over the 32768 rows, chosen so fixed + R*8192 fits ws_size.
  int R = 32768;
  while (R > 1024 && fixed + (size_t)R * 8192 > ws_size) R >>= 1;
  unsigned short* Zc = (unsigned short*)take((size_t)R * 8192);  // gated z chunk [R][4096] bf16

  // ---- one-time prep ----
  k_cast_bf16<<<16384, TPB, 0, stream>>>(x, Xb, 4194304);
  k_cast_bf16<<<2048, TPB, 0, stream>>>(w_out, Wob, 524288);
  k_prep_wmT<<<4096, TPB, 0, stream>>>(w_mrg, WmT);
  k_prep_b1<<<16384, TPB, 0, stream>>>(w_in, b_in, B1t, bb1);
  k_prep_v<<<8, TPB, 0, stream>>>(ln_b, w_out, vbuf);
  k_prep_bias2<<<2, TPB, 0, stream>>>(b_mrg, b_out, vbuf, w_mrg, bias2);
  {
    dim3 g(4, 32);
    k_gemm<2><<<g, TPB, 0, stream>>>(Wob, WmT, 512, W2p, nullptr, nullptr, nullptr, nullptr,
                                     nullptr, ln_g);
  }

  // ---- chunked main pipeline ----
  const int nchunks = 32768 / R;
  for (int ch = 0; ch < nchunks; ++ch) {
    const size_t m0 = (size_t)ch * R;
    hipMemsetAsync(gsum, 0, (size_t)R * 16, stream);
    hipMemsetAsync(gsq, 0, (size_t)R * 16, stream);
    {
      dim3 g(64, R / 128);
      k_gemm<0><<<g, TPB, 0, stream>>>(Xb + m0 * 512, B1t, 512, Zc, nullptr, bb1, gsum, gsq,
                                       nullptr, nullptr);
    }
    k_stats<<<(R * 4 + TPB - 1) / TPB, TPB, 0, stream>>>(gsum, gsq, mu, rs, R * 4);
    k_norm<<<R * 2, TPB, 0, stream>>>(Zc, mu, rs);
    {
      dim3 g(4, R / 128);
      k_gemm<1><<<g, TPB, 0, stream>>>(Zc, W2p, 4096, nullptr, out + m0 * 512, nullptr, nullptr,
                                       nullptr, bias2, nullptr);
    }
  }

  k_final_ln<<<8192, TPB, 0, stream>>>(out, nrm_g, nrm_b);
}

// Round 3
// 1014.986 us; speedup vs baseline: 1.1418x; 1.1418x over previous
//
#include <hip/hip_runtime.h>
#include <stdint.h>

#define TPB 256

typedef short s4v __attribute__((ext_vector_type(4)));
typedef short s8v __attribute__((ext_vector_type(8)));
typedef float f4v __attribute__((ext_vector_type(4)));

__device__ __forceinline__ unsigned short f2bf(float f) {
  union { float f; unsigned u; } v; v.f = f;
  unsigned r = v.u + 0x7FFFu + ((v.u >> 16) & 1u);
  return (unsigned short)(r >> 16);
}
__device__ __forceinline__ float bf2f(unsigned short h) {
  union { unsigned u; float f; } v; v.u = ((unsigned)h) << 16;
  return v.f;
}
__device__ __forceinline__ void gl_lds16(const void* g, void* l) {
  __builtin_amdgcn_global_load_lds(
      (const __attribute__((address_space(1))) void*)g,
      (__attribute__((address_space(3))) void*)l, 16, 0, 0);
}

// ---------------- small prep kernels ----------------

__global__ void k_cast_bf16(const float* __restrict__ src, unsigned short* __restrict__ dst, int n4) {
  int i = blockIdx.x * TPB + threadIdx.x;
  if (i >= n4) return;
  float4 v = ((const float4*)src)[i];
  ushort4 o;
  o.x = f2bf(v.x); o.y = f2bf(v.y); o.z = f2bf(v.z); o.w = f2bf(v.w);
  ((ushort4*)dst)[i] = o;
}

// wmT[dir][d][t] = w_merge[(dir*512+t)*512 + d]  (bf16)
__global__ void k_prep_wmT(const float* __restrict__ wm, unsigned short* __restrict__ dst) {
  int id = blockIdx.x * TPB + threadIdx.x;  // 4*512*512
  int dir = id >> 18, rem = id & 262143, d = rem >> 9, t = rem & 511;
  dst[id] = f2bf(wm[(size_t)(dir * 512 + t) * 512 + d]);
}

// B1t[j][k]: interleaved-by-16 z/gate columns of w_in, transposed. LDS-tiled.
// grid (32 e-tiles, 8 k-tiles, 4 dirs)
__global__ void k_prep_b1(const float* __restrict__ w_in, const float* __restrict__ b_in,
                          unsigned short* __restrict__ B1t, float* __restrict__ bb1) {
  __shared__ float tile[64][65];
  const int e0 = blockIdx.x * 64, k0 = blockIdx.y * 64, dir = blockIdx.z;
  const int tid = threadIdx.x;
  const int lo = tid & 63, hi = tid >> 6;
#pragma unroll
  for (int r = 0; r < 16; ++r) {
    int k = r * 4 + hi;
    tile[k][lo] = w_in[(size_t)(dir * 512 + k0 + k) * 2048 + e0 + lo];
  }
  __syncthreads();
  const int s_ = e0 >> 10;
#pragma unroll
  for (int r = 0; r < 16; ++r) {
    int e = r * 4 + hi;
    int ee = (e0 + e) & 1023;
    int g = dir * 64 + (ee >> 4);
    int j = g * 32 + s_ * 16 + (ee & 15);
    B1t[(size_t)j * 512 + k0 + lo] = f2bf(tile[lo][e]);
    if (k0 == 0 && lo == 0) bb1[j] = b_in[dir * 2048 + s_ * 1024 + ee];
  }
}

// v[dir][t] = sum_e ln_b[dir][e] * w_out[dir][e][t]   grid (4,8)
__global__ void k_prep_v(const float* __restrict__ lnb, const float* __restrict__ wout,
                         float* __restrict__ v) {
  const int dir = blockIdx.x, t0 = blockIdx.y * 64;
  const int lt = threadIdx.x & 63, eg = threadIdx.x >> 6;
  float s = 0.f;
  for (int i = 0; i < 256; ++i) {
    int e = eg * 256 + i;
    s += lnb[dir * 1024 + e] * wout[(size_t)(dir * 1024 + e) * 512 + t0 + lt];
  }
  __shared__ float red[4][64];
  red[eg][lt] = s;
  __syncthreads();
  if (threadIdx.x < 64)
    v[dir * 512 + t0 + lt] = red[0][lt] + red[1][lt] + red[2][lt] + red[3][lt];
}

// bias2 += partial sums; grid (8 d-blocks, 4 f-segs); bias2 pre-zeroed
__global__ void k_prep_bias2(const float* __restrict__ bmerge, const float* __restrict__ bout,
                             const float* __restrict__ v, const float* __restrict__ wmerge,
                             float* __restrict__ bias2) {
  const int d0 = blockIdx.x * 64, fs = blockIdx.y * 512;
  const int ld = threadIdx.x & 63, fg = threadIdx.x >> 6;
  float s = 0.f;
  for (int i = 0; i < 128; ++i) {
    int f = fs + fg * 128 + i;
    s += (bout[f] + v[f]) * wmerge[(size_t)f * 512 + d0 + ld];
  }
  __shared__ float red[4][64];
  red[fg][ld] = s;
  __syncthreads();
  if (threadIdx.x < 64) {
    float r = red[0][ld] + red[1][ld] + red[2][ld] + red[3][ld];
    if (blockIdx.y == 0) r += bmerge[d0 + ld];
    atomicAdd(&bias2[d0 + ld], r);
  }
}

// S[dcol*4+d] = sum_j W2p[dcol][d*1024+j]   grid 512 x 256
__global__ void k_colsum(const unsigned short* __restrict__ W2p, float* __restrict__ S) {
  const int dcol = blockIdx.x, tid = threadIdx.x;
  const unsigned short* p = W2p + (size_t)dcol * 4096 + tid * 16;
  s8v a = *(const s8v*)p, b = *(const s8v*)(p + 8);
  float s = 0.f;
#pragma unroll
  for (int j = 0; j < 8; ++j) s += bf2f((unsigned short)a[j]) + bf2f((unsigned short)b[j]);
#pragma unroll
  for (int mk = 1; mk < 64; mk <<= 1) s += __shfl_xor(s, mk);
  if ((tid & 63) == 0) S[dcol * 4 + (tid >> 6)] = s;
}

// ---------------- GEMM template ----------------
// C[M,N] = A[M,K] * Bt[N,K]^T, bf16, 128x128 tile, BK=64, 4 waves.
// MODE 0: K1: gate epilogue, packed-u32 permuted Z write, atomic LN stats.
//         params: U16out=Z, bb1, gsum, gsq
// MODE 1: K2 with LN folded (running r-rescale at dir boundaries + mu*r*S corr).
//         params: F32out=out, gsum=rs, gsq=mur, bias2, lng=S
// MODE 2: W2' build (scale ln_g, permuted transposed write). params: U16out=W2p, lng
template <int MODE>
__launch_bounds__(TPB, 2)
__global__ void k_gemm(const unsigned short* __restrict__ A,
                       const unsigned short* __restrict__ Bt, int K,
                       unsigned short* __restrict__ U16out, float* __restrict__ F32out,
                       const float* __restrict__ bb1, float* __restrict__ gsum,
                       float* __restrict__ gsq, const float* __restrict__ bias2,
                       const float* __restrict__ lng) {
  __shared__ char lds[2][32768];
  const int tid = threadIdx.x;
  int bN, bM;
  if (MODE == 2) { bN = blockIdx.x; bM = blockIdx.y; }
  else if (MODE == 0) { int id = blockIdx.x; bM = (id & 7) + ((id >> 9) << 3); bN = (id >> 3) & 63; }
  else { int id = blockIdx.x; bM = (id & 7) + ((id >> 5) << 3); bN = (id >> 3) & 3; }
  const int lane = tid & 63, wid = tid >> 6;
  const int wm = wid >> 1, wn = wid & 1;
  const int q = lane >> 4, c = lane & 15;

  const unsigned short* Bte = Bt;
  if (MODE == 2) Bte += (size_t)(bM >> 3) * (512 * 512);

  const size_t ldab = (size_t)K * 2;
  const char* Ab = (const char*)A + (size_t)bM * 128 * ldab;
  const char* Bb = (const char*)Bte + (size_t)bN * 128 * ldab;

  f4v acc[4][4];
  {
    f4v z = {0.f, 0.f, 0.f, 0.f};
#pragma unroll
    for (int m = 0; m < 4; ++m)
#pragma unroll
      for (int n = 0; n < 4; ++n) acc[m][n] = z;
  }

  float rsv[16];
  if (MODE == 1) {
#pragma unroll
    for (int i = 0; i < 16; ++i) {
      int row = bM * 128 + wm * 64 + (i >> 2) * 16 + q * 4 + (i & 3);
      rsv[i] = gsum[row * 4 + 0];  // gsum == rs
    }
  }

  const int NT = K >> 6;

  auto stage = [&](int buf, int kt) {
    const size_t kb = (size_t)kt << 7;
#pragma unroll
    for (int i = 0; i < 4; ++i) {
      int ci = tid + i * 256;
      int r = ci >> 3, cc = ci & 7;
      int ccs = cc ^ (r & 7);
      gl_lds16(Ab + (size_t)r * ldab + kb + ccs * 16,
               (void*)(lds[buf] + wid * 1024 + i * 4096));
    }
#pragma unroll
    for (int i = 0; i < 4; ++i) {
      int ci = tid + i * 256;
      int r = ci >> 3, cc = ci & 7;
      int ccs = cc ^ (r & 7);
      gl_lds16(Bb + (size_t)r * ldab + kb + ccs * 16,
               (void*)(lds[buf] + 16384 + wid * 1024 + i * 4096));
    }
  };

  stage(0, 0);
  __syncthreads();

  for (int t = 0; t < NT; ++t) {
    const int cur = t & 1;
    if (t + 1 < NT) stage(cur ^ 1, t + 1);
    const char* L = lds[cur];

    if (MODE == 1 && t && (t & 15) == 0) {
      // dir boundary: acc *= r_{d-1}/r_d  (running rescale)
      const int dnew = t >> 4;
#pragma unroll
      for (int i = 0; i < 16; ++i) {
        int row = bM * 128 + wm * 64 + (i >> 2) * 16 + q * 4 + (i & 3);
        float nr = gsum[row * 4 + dnew];
        float f = rsv[i] / nr;
        rsv[i] = nr;
#pragma unroll
        for (int n = 0; n < 4; ++n) acc[i >> 2][n][i & 3] *= f;
      }
    }

#pragma unroll
    for (int kk = 0; kk < 2; ++kk) {
      s8v af[4], bfr[4];
#pragma unroll
      for (int m = 0; m < 4; ++m) {
        int r = wm * 64 + m * 16 + c;
        int sw = ((r << 7) + (kk << 6) + (q << 3)) ^ ((r & 7) << 4);
        s4v lo = *(const s4v*)(L + sw);
        s4v hi = *(const s4v*)(L + (sw ^ 32));
        af[m] = __builtin_shufflevector(lo, hi, 0, 1, 2, 3, 4, 5, 6, 7);
      }
#pragma unroll
      for (int n = 0; n < 4; ++n) {
        int r = wn * 64 + n * 16 + c;
        int sw = ((r << 7) + (kk << 6) + (q << 3)) ^ ((r & 7) << 4);
        s4v lo = *(const s4v*)(L + 16384 + sw);
        s4v hi = *(const s4v*)(L + 16384 + (sw ^ 32));
        bfr[n] = __builtin_shufflevector(lo, hi, 0, 1, 2, 3, 4, 5, 6, 7);
      }
#pragma unroll
      for (int m = 0; m < 4; ++m)
#pragma unroll
        for (int n = 0; n < 4; ++n)
          acc[m][n] = __builtin_amdgcn_mfma_f32_16x16x32_bf16(af[m], bfr[n], acc[m][n], 0, 0, 0);
    }
    __syncthreads();
  }

  if (MODE == 0) {
    const int dir = bN >> 4;
    const int jb = bN * 128 + wn * 64 + c;
    const float bz0 = bb1[jb], bg0 = bb1[jb + 16], bz1 = bb1[jb + 32], bg1 = bb1[jb + 48];
    unsigned* Zp = (unsigned*)U16out;
    const int colu = dir * 512 + ((bN & 15) * 2 + wn) * 16 + c;
    float s1[4][4], s2[4][4];
#pragma unroll
    for (int m = 0; m < 4; ++m)
#pragma unroll
      for (int r = 0; r < 4; ++r) {
        int row = bM * 128 + wm * 64 + m * 16 + q * 4 + r;
        float z0 = acc[m][0][r] + bz0, g0 = acc[m][1][r] + bg0;
        float z1 = acc[m][2][r] + bz1, g1 = acc[m][3][r] + bg1;
        float v0 = z0 * (1.f / (1.f + __expf(-z0))) * (1.f / (1.f + __expf(-g0)));
        float v1 = z1 * (1.f / (1.f + __expf(-z1))) * (1.f / (1.f + __expf(-g1)));
        Zp[(size_t)row * 2048 + colu] = (unsigned)f2bf(v0) | ((unsigned)f2bf(v1) << 16);
        s1[m][r] = v0 + v1;
        s2[m][r] = v0 * v0 + v1 * v1;
      }
#pragma unroll
    for (int m = 0; m < 4; ++m)
#pragma unroll
      for (int r = 0; r < 4; ++r) {
        float a1 = s1[m][r], a2 = s2[m][r];
#pragma unroll
        for (int mk = 1; mk < 16; mk <<= 1) {
          a1 += __shfl_xor(a1, mk);
          a2 += __shfl_xor(a2, mk);
        }
        if (c == 0) {
          int row = bM * 128 + wm * 64 + m * 16 + q * 4 + r;
          atomicAdd(&gsum[row * 4 + dir], a1);
          atomicAdd(&gsq[row * 4 + dir], a2);
        }
      }
  }

  if (MODE == 1) {
    float4 S4[4], b2[1];
    float bias[4];
#pragma unroll
    for (int n = 0; n < 4; ++n) {
      int col = bN * 128 + wn * 64 + n * 16 + c;
      S4[n] = ((const float4*)lng)[col];  // lng == S
      bias[n] = bias2[col];
    }
#pragma unroll
    for (int m = 0; m < 4; ++m)
#pragma unroll
      for (int r = 0; r < 4; ++r) {
        int row = bM * 128 + wm * 64 + m * 16 + q * 4 + r;
        float4 mu4 = ((const float4*)gsq)[row];  // gsq == mur
        float rv = rsv[m * 4 + r];
#pragma unroll
        for (int n = 0; n < 4; ++n) {
          int col = bN * 128 + wn * 64 + n * 16 + c;
          float corr = mu4.x * S4[n].x + mu4.y * S4[n].y + mu4.z * S4[n].z + mu4.w * S4[n].w;
          F32out[(size_t)row * 512 + col] = acc[m][n][r] * rv - corr + bias[n];
        }
      }
  }

  if (MODE == 2) {
#pragma unroll
    for (int m = 0; m < 4; ++m)
#pragma unroll
      for (int r = 0; r < 4; ++r) {
        int fl = bM * 128 + wm * 64 + m * 16 + q * 4 + r;
        float sc = lng[fl];
        int dirf = fl >> 10, e = fl & 1023, ch = e >> 4, cc = e & 15;
        int fnew = dirf * 1024 + (ch >> 1) * 32 + cc * 2 + (ch & 1);
#pragma unroll
        for (int n = 0; n < 4; ++n) {
          int d = bN * 128 + wn * 64 + n * 16 + c;
          U16out[(size_t)d * 4096 + fnew] = f2bf(acc[m][n][r] * sc);
        }
      }
  }
}

// ---------------- post kernels ----------------

__global__ void k_stats(const float* __restrict__ gsum, const float* __restrict__ gsq,
                        float* __restrict__ rs, float* __restrict__ mur, int n) {
  int i = blockIdx.x * TPB + threadIdx.x;
  if (i >= n) return;
  float m = gsum[i] * (1.f / 1024.f);
  float v = gsq[i] * (1.f / 1024.f) - m * m;
  float r = rsqrtf(fmaxf(v, 0.f) + 1e-5f);
  rs[i] = r;
  mur[i] = m * r;
}

__global__ void k_final_ln(float* __restrict__ out, const float* __restrict__ g,
                           const float* __restrict__ b) {
  int row = blockIdx.x * 4 + (threadIdx.x >> 6);
  int lane = threadIdx.x & 63;
  float* p = out + (size_t)row * 512;
  float x[8];
  *(float4*)&x[0] = *(const float4*)(p + lane * 4);
  *(float4*)&x[4] = *(const float4*)(p + 256 + lane * 4);
  float s = 0.f;
#pragma unroll
  for (int j = 0; j < 8; ++j) s += x[j];
#pragma unroll
  for (int mk = 1; mk < 64; mk <<= 1) s += __shfl_xor(s, mk);
  float mean = s * (1.f / 512.f);
  float vs = 0.f;
#pragma unroll
  for (int j = 0; j < 8; ++j) { float d = x[j] - mean; vs += d * d; }
#pragma unroll
  for (int mk = 1; mk < 64; mk <<= 1) vs += __shfl_xor(vs, mk);
  float rstd = rsqrtf(vs * (1.f / 512.f) + 1e-5f);
  float gg[8], bb[8];
  *(float4*)&gg[0] = *(const float4*)(g + lane * 4);
  *(float4*)&gg[4] = *(const float4*)(g + 256 + lane * 4);
  *(float4*)&bb[0] = *(const float4*)(b + lane * 4);
  *(float4*)&bb[4] = *(const float4*)(b + 256 + lane * 4);
#pragma unroll
  for (int j = 0; j < 8; ++j) x[j] = (x[j] - mean) * rstd * gg[j] + bb[j];
  *(float4*)(p + lane * 4) = *(float4*)&x[0];
  *(float4*)(p + 256 + lane * 4) = *(float4*)&x[4];
}

// ---------------- launch ----------------

extern "C" void kernel_launch(void* const* d_in, const int* in_sizes, int n_in,
                              void* d_out, int out_size, void* d_ws, size_t ws_size,
                              hipStream_t stream) {
  const float* x     = (const float*)d_in[0];
  const float* w_in  = (const float*)d_in[1];
  const float* b_in  = (const float*)d_in[2];
  const float* ln_g  = (const float*)d_in[3];
  const float* ln_b  = (const float*)d_in[4];
  const float* w_out = (const float*)d_in[5];
  const float* b_out = (const float*)d_in[6];
  const float* w_mrg = (const float*)d_in[7];
  const float* b_mrg = (const float*)d_in[8];
  const float* nrm_g = (const float*)d_in[9];
  const float* nrm_b = (const float*)d_in[10];
  float* out = (float*)d_out;

  char* ws = (char*)d_ws;
  size_t off = 0;
  auto take = [&](size_t bytes) {
    char* p = ws + off;
    off += (bytes + 255) & ~(size_t)255;
    return p;
  };
  unsigned short* Xb    = (unsigned short*)take(33554432);   // x bf16 [32768][512]
  unsigned short* B1t   = (unsigned short*)take(8388608);    // w_in arranged [8192][512]
  float*          bb1   = (float*)take(32768);
  unsigned short* Wob   = (unsigned short*)take(4194304);    // w_out bf16 [4096][512]
  unsigned short* WmT   = (unsigned short*)take(2097152);    // w_merge^T bf16 [4][512][512]
  unsigned short* W2p   = (unsigned short*)take(4194304);    // combined W2' [512][4096] (permuted f)
  float*          vbuf  = (float*)take(8192);
  float*          bias2 = (float*)take(2048);
  float*          Sbuf  = (float*)take(8192);                // S[dcol][4]
  float*          gsum  = (float*)take(524288);
  float*          gsq   = (float*)take(524288);
  float*          rs    = (float*)take(524288);
  float*          mur   = (float*)take(524288);
  size_t fixed = off;

  int R = 32768;
  while (R > 1024 && fixed + (size_t)R * 8192 > ws_size) R >>= 1;
  unsigned short* Zc = (unsigned short*)take((size_t)R * 8192);  // gated z chunk (permuted cols)

  // ---- one-time prep ----
  hipMemsetAsync(bias2, 0, 2048, stream);
  k_cast_bf16<<<16384, TPB, 0, stream>>>(x, Xb, 4194304);
  k_cast_bf16<<<2048, TPB, 0, stream>>>(w_out, Wob, 524288);
  k_prep_wmT<<<4096, TPB, 0, stream>>>(w_mrg, WmT);
  {
    dim3 g(32, 8, 4);
    k_prep_b1<<<g, TPB, 0, stream>>>(w_in, b_in, B1t, bb1);
  }
  {
    dim3 g(4, 8);
    k_prep_v<<<g, TPB, 0, stream>>>(ln_b, w_out, vbuf);
  }
  {
    dim3 g(8, 4);
    k_prep_bias2<<<g, TPB, 0, stream>>>(b_mrg, b_out, vbuf, w_mrg, bias2);
  }
  {
    dim3 g(4, 32);
    k_gemm<2><<<g, TPB, 0, stream>>>(Wob, WmT, 512, W2p, nullptr, nullptr, nullptr, nullptr,
                                     nullptr, ln_g);
  }
  k_colsum<<<512, TPB, 0, stream>>>(W2p, Sbuf);

  // ---- chunked main pipeline ----
  const int nchunks = 32768 / R;
  for (int ch = 0; ch < nchunks; ++ch) {
    const size_t m0 = (size_t)ch * R;
    const int nbM = R / 128;
    hipMemsetAsync(gsum, 0, (size_t)R * 16, stream);
    hipMemsetAsync(gsq, 0, (size_t)R * 16, stream);
    k_gemm<0><<<64 * nbM, TPB, 0, stream>>>(Xb + m0 * 512, B1t, 512, Zc, nullptr, bb1, gsum, gsq,
                                            nullptr, nullptr);
    k_stats<<<(R * 4 + TPB - 1) / TPB, TPB, 0, stream>>>(gsum, gsq, rs, mur, R * 4);
    k_gemm<1><<<4 * nbM, TPB, 0, stream>>>(Zc, W2p, 4096, nullptr, out + m0 * 512, nullptr, rs,
                                           mur, bias2, Sbuf);
  }

  k_final_ln<<<8192, TPB, 0, stream>>>(out, nrm_g, nrm_b);
}